// Round 14
// baseline (474.633 us; speedup 1.0000x reference)
//
#include <hip/hip_runtime.h>

#define H 1024
#define T_STEPS 64
#define S_MEM 512
#define VA 30
#define VW 30000

typedef unsigned long long u64;
typedef __attribute__((ext_vector_type(8))) short short8;
typedef __attribute__((ext_vector_type(4))) float f32x4;

__device__ __forceinline__ float sigmf(float x) { return 1.f / (1.f + expf(-x)); }
__device__ __forceinline__ unsigned short f2bf(float f) {
  unsigned u = __float_as_uint(f);
  return (unsigned short)((u + 0x7FFFu + ((u >> 16) & 1u)) >> 16);
}
__device__ __forceinline__ short8 ldcvt8(const float* p) {
  float4 f0 = *(const float4*)p;
  float4 f1 = *(const float4*)(p + 4);
  short8 r;
  r[0] = (short)f2bf(f0.x); r[1] = (short)f2bf(f0.y);
  r[2] = (short)f2bf(f0.z); r[3] = (short)f2bf(f0.w);
  r[4] = (short)f2bf(f1.x); r[5] = (short)f2bf(f1.y);
  r[6] = (short)f2bf(f1.z); r[7] = (short)f2bf(f1.w);
  return r;
}
__device__ __forceinline__ void stage_sw(float* S, int nn, int km, float4 v) {
  int c2 = ((nn >> 2) ^ km) & 15, p = nn & 3;
  S[(km * 4 + 0) * 64 + c2 * 4 + p] = v.x;
  S[(km * 4 + 1) * 64 + c2 * 4 + p] = v.y;
  S[(km * 4 + 2) * 64 + c2 * 4 + p] = v.z;
  S[(km * 4 + 3) * 64 + c2 * 4 + p] = v.w;
}
__device__ __forceinline__ void mm_inner(const float* As, const float* Bs,
                                         int ridx, int cidx, float (&acc)[4][4]) {
  const float4* As4 = (const float4*)As;
  const float4* Bs4 = (const float4*)Bs;
  __syncthreads();
#pragma unroll 8
  for (int kk = 0; kk < 64; ++kk) {
    int sw = kk >> 2;
    float4 a4 = As4[kk * 16 + ((ridx ^ sw) & 15)];
    float4 b4 = Bs4[kk * 16 + ((cidx ^ sw) & 15)];
    float av[4] = {a4.x, a4.y, a4.z, a4.w};
    float bv[4] = {b4.x, b4.y, b4.z, b4.w};
#pragma unroll
    for (int i = 0; i < 4; ++i)
#pragma unroll
      for (int j = 0; j < 4; ++j) acc[i][j] += av[i] * bv[j];
  }
  __syncthreads();
}

// ================= k_head: init + xg GEMM (embeddings gathered in staging) =================
__global__ __launch_bounds__(256) void k_head(
    const int* __restrict__ actions, const int* __restrict__ words,
    const float* __restrict__ act_emb, const float* __restrict__ word_emb,
    const float* __restrict__ Wih_t, const float* __restrict__ Wih_a,
    float* __restrict__ Pxg_t, float* __restrict__ Pxg_a,
    float* __restrict__ fin, u64* __restrict__ htag) {
  int x = blockIdx.x, tid = threadIdx.x, y = blockIdx.y, z = blockIdx.z;
  if (x == 64) {
    int bi = y * 2 + z;
    uint4* hq = (uint4*)(htag) + (size_t)bi * 16384;
    uint4 zz = make_uint4(0, 0, 0, 0);
    for (int i = tid; i < 16384; i += 256) hq[i] = zz;
    if (bi == 0)
      for (int i = tid; i < 3072; i += 256) fin[i] = 0.f;   // term/act/stack at t=0
    if (bi == 1) {
      for (int j = tid; j < 63 * 1024; j += 256) {
        int t = j >> 10, i2 = j & 1023;
        fin[(size_t)(t + 1) * 4096 + 2048 + i2] = word_emb[(size_t)words[t] * 1024 + i2];
      }
    }
    return;
  }
  __shared__ __align__(16) float As[4096], Bs[4096];
  const int* idxs = z ? actions : words;
  const float* emb = z ? act_emb : word_emb;
  const float* B = z ? Wih_a : Wih_t;
  float* Pp = z ? Pxg_a : Pxg_t;
  int cidx = tid & 15, ridx = tid >> 4;
  int n0 = x * 64, kbeg = y * 512;
  float acc[4][4] = {};
  for (int k0 = kbeg; k0 < kbeg + 512; k0 += 64) {
#pragma unroll
    for (int i = 0; i < 4; ++i) {
      int f = tid + i * 256, rr = f >> 4, km = f & 15;
      float4 v = *(const float4*)&emb[(size_t)idxs[rr] * 1024 + k0 + km * 4];
      stage_sw(As, rr, km, v);
    }
#pragma unroll
    for (int i = 0; i < 4; ++i) {
      int f = tid + i * 256, nn = f >> 4, km = f & 15;
      float4 v = *(const float4*)&B[(size_t)(n0 + nn) * 1024 + k0 + km * 4];
      stage_sw(Bs, nn, km, v);
    }
    mm_inner(As, Bs, ridx, cidx, acc);
  }
  int gcol = n0 + cidx * 4;
  float* P = Pp + (size_t)y * 262144;
#pragma unroll
  for (int i = 0; i < 4; ++i) {
    int row = ridx * 4 + i;
    *(float4*)&P[(size_t)row * 4096 + gcol] =
        make_float4(acc[i][0], acc[i][1], acc[i][2], acc[i][3]);
  }
}

// ================= persistent recurrence (R10/R12-proven) =================
__global__ __launch_bounds__(256, 1) void k_recur(
    const float* __restrict__ Whh_term, const float* __restrict__ Whh_act,
    const float* __restrict__ Pxg_term, const float* __restrict__ Pxg_act,
    const float* __restrict__ bih_t, const float* __restrict__ bhh_t,
    const float* __restrict__ bih_a, const float* __restrict__ bhh_a,
    float* __restrict__ fin, u64* __restrict__ htag) {
  __shared__ float hs[2][32 * 36];
  __shared__ float xgs[63 * 32];
  int b = blockIdx.x, tid = threadIdx.x;
  int lstm = b >> 7, k0 = (b & 127) * 8;
  const float* Whh = lstm ? Whh_act : Whh_term;
  const float* Pxg = lstm ? Pxg_act : Pxg_term;
  const float* bih = lstm ? bih_a : bih_t;
  const float* bhh = lstm ? bhh_a : bhh_t;
  int d = tid >> 5, p = tid & 31;

  float wreg[128];
#pragma unroll
  for (int g = 0; g < 4; ++g) {
    const float* wrow = Whh + (size_t)(g * 1024 + k0 + d) * 1024 + p * 32;
#pragma unroll
    for (int i = 0; i < 32; i += 4) {
      float4 v = *(const float4*)(wrow + i);
      wreg[g * 32 + i]     = v.x; wreg[g * 32 + i + 1] = v.y;
      wreg[g * 32 + i + 2] = v.z; wreg[g * 32 + i + 3] = v.w;
    }
  }
#pragma unroll
  for (int i = 0; i < 128; ++i) asm volatile("" : "+v"(wreg[i]));

  for (int i = tid; i < 63 * 32; i += 256) {
    int rr = i & 31, t2 = i >> 5;
    int row2 = (rr >> 3) * 1024 + k0 + (rr & 7);
    xgs[i] = Pxg[(size_t)t2 * 4096 + row2] + Pxg[262144 + (size_t)t2 * 4096 + row2] +
             bih[row2] + bhh[row2];
  }
  float c_loc = 0.f;

  for (int t = 0; t < 63; ++t) {
    float* hb = hs[t & 1];
    if (t > 0) {
      const u64* src = htag + (size_t)t * 2048 + lstm * 1024;
      u64 v0 = __hip_atomic_load(&src[tid], __ATOMIC_RELAXED, __HIP_MEMORY_SCOPE_AGENT);
      u64 v1 = __hip_atomic_load(&src[tid + 256], __ATOMIC_RELAXED, __HIP_MEMORY_SCOPE_AGENT);
      u64 v2 = __hip_atomic_load(&src[tid + 512], __ATOMIC_RELAXED, __HIP_MEMORY_SCOPE_AGENT);
      u64 v3 = __hip_atomic_load(&src[tid + 768], __ATOMIC_RELAXED, __HIP_MEMORY_SCOPE_AGENT);
      while ((unsigned)(v0 >> 32) != (unsigned)t) {
        __builtin_amdgcn_s_sleep(1);
        v0 = __hip_atomic_load(&src[tid], __ATOMIC_RELAXED, __HIP_MEMORY_SCOPE_AGENT);
      }
      while ((unsigned)(v1 >> 32) != (unsigned)t) {
        __builtin_amdgcn_s_sleep(1);
        v1 = __hip_atomic_load(&src[tid + 256], __ATOMIC_RELAXED, __HIP_MEMORY_SCOPE_AGENT);
      }
      while ((unsigned)(v2 >> 32) != (unsigned)t) {
        __builtin_amdgcn_s_sleep(1);
        v2 = __hip_atomic_load(&src[tid + 512], __ATOMIC_RELAXED, __HIP_MEMORY_SCOPE_AGENT);
      }
      while ((unsigned)(v3 >> 32) != (unsigned)t) {
        __builtin_amdgcn_s_sleep(1);
        v3 = __hip_atomic_load(&src[tid + 768], __ATOMIC_RELAXED, __HIP_MEMORY_SCOPE_AGENT);
      }
      hb[((tid) >> 5) * 36 + (tid & 31)]       = __uint_as_float((unsigned)v0);
      hb[((tid + 256) >> 5) * 36 + (tid & 31)] = __uint_as_float((unsigned)v1);
      hb[((tid + 512) >> 5) * 36 + (tid & 31)] = __uint_as_float((unsigned)v2);
      hb[((tid + 768) >> 5) * 36 + (tid & 31)] = __uint_as_float((unsigned)v3);
    } else {
#pragma unroll
      for (int j = 0; j < 4; ++j) {
        int idx = tid + j * 256;
        hb[(idx >> 5) * 36 + (idx & 31)] = 0.f;
      }
    }
    __syncthreads();

    const float* hp = hb + p * 36;
    float s0 = 0.f, s1 = 0.f, s2 = 0.f, s3 = 0.f;
#pragma unroll
    for (int i = 0; i < 32; i += 4) {
      float4 hv = *(const float4*)&hp[i];
      s0 += wreg[i] * hv.x + wreg[i + 1] * hv.y + wreg[i + 2] * hv.z + wreg[i + 3] * hv.w;
      s1 += wreg[32 + i] * hv.x + wreg[33 + i] * hv.y + wreg[34 + i] * hv.z + wreg[35 + i] * hv.w;
      s2 += wreg[64 + i] * hv.x + wreg[65 + i] * hv.y + wreg[66 + i] * hv.z + wreg[67 + i] * hv.w;
      s3 += wreg[96 + i] * hv.x + wreg[97 + i] * hv.y + wreg[98 + i] * hv.z + wreg[99 + i] * hv.w;
    }
#pragma unroll
    for (int m = 1; m <= 16; m <<= 1) {
      s0 += __shfl_xor(s0, m); s1 += __shfl_xor(s1, m);
      s2 += __shfl_xor(s2, m); s3 += __shfl_xor(s3, m);
    }
    if (p == 0) {
      float gi = s0 + xgs[t * 32 + d];
      float gf = s1 + xgs[t * 32 + 8 + d];
      float gg = s2 + xgs[t * 32 + 16 + d];
      float go = s3 + xgs[t * 32 + 24 + d];
      float c2 = sigmf(gf) * c_loc + sigmf(gi) * tanhf(gg);
      float h2 = sigmf(go) * tanhf(c2);
      c_loc = c2;
      fin[(size_t)(t + 1) * 4096 + lstm * 1024 + k0 + d] = h2;
      __hip_atomic_store(&htag[(size_t)(t + 1) * 2048 + lstm * 1024 + k0 + d],
                         (((u64)(t + 1)) << 32) | (u64)__float_as_uint(h2),
                         __ATOMIC_RELAXED, __HIP_MEMORY_SCOPE_AGENT);
    }
  }
}

// ====== generic bf16-MFMA GEMM: out[64,N] = A[64,K](fp32) @ B[N,K](fp32)^T + bias ======
// Block = 16 output cols x 64 rows. 4 waves split K; LDS cross-wave reduce; fused
// bias (+relu). Both operands converted fp32->bf16 in-register on load.
// blockIdx.y selects (B, bias, out) pair (for the dual ha/hw launch).
__global__ __launch_bounds__(256) void k_mfma_bt(
    const float* __restrict__ A, int lda,
    const float* __restrict__ B0, const float* __restrict__ B1, int ldb,
    const float* __restrict__ bias0, const float* __restrict__ bias1,
    float* __restrict__ out0, float* __restrict__ out1, int ldc,
    int K, int relu) {
  __shared__ __align__(16) float sm[4 * 1024];
  const float* B = blockIdx.y ? B1 : B0;
  const float* bias = blockIdx.y ? bias1 : bias0;
  float* out = blockIdx.y ? out1 : out0;
  int tid = threadIdx.x;
  int w = tid >> 6, lane = tid & 63;
  int col0 = blockIdx.x * 16;
  int klen = K >> 2;                 // per-wave K segment (multiple of 32)
  int kbeg = w * klen;
  int kg = kbeg + (lane >> 4) * 8;
  const float* brow = B + (size_t)(col0 + (lane & 15)) * ldb + kg;
  const float* arow = A + (size_t)(lane & 15) * lda + kg;
  f32x4 acc0 = {0.f, 0.f, 0.f, 0.f}, acc1 = acc0, acc2 = acc0, acc3 = acc0;

  short8 bf = ldcvt8(brow);
  short8 a0 = ldcvt8(arow);
  short8 a1 = ldcvt8(arow + 16 * lda);
  short8 a2 = ldcvt8(arow + 32 * lda);
  short8 a3 = ldcvt8(arow + 48 * lda);
  for (int k0 = 0; k0 < klen - 32; k0 += 32) {
    short8 bf_n = ldcvt8(brow + k0 + 32);
    short8 a0n = ldcvt8(arow + k0 + 32);
    short8 a1n = ldcvt8(arow + 16 * lda + k0 + 32);
    short8 a2n = ldcvt8(arow + 32 * lda + k0 + 32);
    short8 a3n = ldcvt8(arow + 48 * lda + k0 + 32);
    acc0 = __builtin_amdgcn_mfma_f32_16x16x32_bf16(a0, bf, acc0, 0, 0, 0);
    acc1 = __builtin_amdgcn_mfma_f32_16x16x32_bf16(a1, bf, acc1, 0, 0, 0);
    acc2 = __builtin_amdgcn_mfma_f32_16x16x32_bf16(a2, bf, acc2, 0, 0, 0);
    acc3 = __builtin_amdgcn_mfma_f32_16x16x32_bf16(a3, bf, acc3, 0, 0, 0);
    bf = bf_n; a0 = a0n; a1 = a1n; a2 = a2n; a3 = a3n;
  }
  acc0 = __builtin_amdgcn_mfma_f32_16x16x32_bf16(a0, bf, acc0, 0, 0, 0);
  acc1 = __builtin_amdgcn_mfma_f32_16x16x32_bf16(a1, bf, acc1, 0, 0, 0);
  acc2 = __builtin_amdgcn_mfma_f32_16x16x32_bf16(a2, bf, acc2, 0, 0, 0);
  acc3 = __builtin_amdgcn_mfma_f32_16x16x32_bf16(a3, bf, acc3, 0, 0, 0);

  // stash wave-local 64x16 tile: D(row, col) row = t*16 + (lane>>4)*4 + j, col = lane&15
  {
    int rbase = (lane >> 4) * 4, c = lane & 15;
    float* smw = sm + w * 1024;
#pragma unroll
    for (int j = 0; j < 4; ++j) {
      smw[(rbase + j) * 16 + c]      = acc0[j];
      smw[(16 + rbase + j) * 16 + c] = acc1[j];
      smw[(32 + rbase + j) * 16 + c] = acc2[j];
      smw[(48 + rbase + j) * 16 + c] = acc3[j];
    }
  }
  __syncthreads();
  // cross-wave reduce + bias (+relu); thread handles 4 consecutive elems (one row chunk)
  {
    const float4* sm4 = (const float4*)sm;
    float4 v = sm4[tid];
    float4 v1 = sm4[256 + tid], v2 = sm4[512 + tid], v3 = sm4[768 + tid];
    v.x += v1.x + v2.x + v3.x;
    v.y += v1.y + v2.y + v3.y;
    v.z += v1.z + v2.z + v3.z;
    v.w += v1.w + v2.w + v3.w;
    int e0 = tid * 4;
    int row = e0 >> 4, cofs = e0 & 15;
    float4 b = *(const float4*)&bias[col0 + cofs];
    v.x += b.x; v.y += b.y; v.z += b.z; v.w += b.w;
    if (relu) {
      v.x = fmaxf(v.x, 0.f); v.y = fmaxf(v.y, 0.f);
      v.z = fmaxf(v.z, 0.f); v.w = fmaxf(v.w, 0.f);
    }
    *(float4*)&out[(size_t)row * ldc + col0 + cofs] = v;
  }
}

// ---------------- attn partials: attn[64,512], A = qbuf (fp32), splitk=8 ----------------
__global__ __launch_bounds__(256) void k_attn2(
    const float* __restrict__ qbuf, const float* __restrict__ mem,
    float* __restrict__ Pa) {
  __shared__ __align__(16) float As[4096], Bs[4096];
  int tid = threadIdx.x, cidx = tid & 15, ridx = tid >> 4;
  int n0 = blockIdx.x * 64, kbeg = blockIdx.y * 128;
  float acc[4][4] = {};
  for (int k0 = kbeg; k0 < kbeg + 128; k0 += 64) {
#pragma unroll
    for (int i = 0; i < 4; ++i) {
      int f = tid + i * 256, rr = f >> 4, km = f & 15;
      float4 v = *(const float4*)&qbuf[(size_t)rr * 1024 + k0 + km * 4];
      stage_sw(As, rr, km, v);
    }
#pragma unroll
    for (int i = 0; i < 4; ++i) {
      int f = tid + i * 256, nn = f >> 4, km = f & 15;
      float4 v = *(const float4*)&mem[(size_t)(n0 + nn) * 1024 + k0 + km * 4];
      stage_sw(Bs, nn, km, v);
    }
    mm_inner(As, Bs, ridx, cidx, acc);
  }
  int gcol = n0 + cidx * 4;
  float* P = Pa + (size_t)blockIdx.y * 32768;
#pragma unroll
  for (int i = 0; i < 4; ++i) {
    int row = ridx * 4 + i;
    *(float4*)&P[(size_t)row * 512 + gcol] =
        make_float4(acc[i][0], acc[i][1], acc[i][2], acc[i][3]);
  }
}

// ---------------- ctx: fin[:,3072:4096] = sum8(Pa) @ memory  (splitk=1, K=512) ----------------
__global__ __launch_bounds__(256) void k_ctx2(
    const float* __restrict__ Pa, const float* __restrict__ mem,
    float* __restrict__ fin) {
  __shared__ __align__(16) float As[4096], Bs[4096];
  int tid = threadIdx.x, cidx = tid & 15, ridx = tid >> 4;
  int n0 = blockIdx.x * 64;
  float acc[4][4] = {};
  for (int k0 = 0; k0 < 512; k0 += 64) {
#pragma unroll
    for (int i = 0; i < 4; ++i) {
      int f = tid + i * 256, rr = f >> 4, km = f & 15;
      int col = k0 + km * 4;
      float4 v = make_float4(0.f, 0.f, 0.f, 0.f);
#pragma unroll
      for (int s = 0; s < 8; ++s) {
        float4 p = *(const float4*)&Pa[(size_t)s * 32768 + (size_t)rr * 512 + col];
        v.x += p.x; v.y += p.y; v.z += p.z; v.w += p.w;
      }
      stage_sw(As, rr, km, v);
    }
#pragma unroll
    for (int i = 0; i < 4; ++i) {
      int f = tid + i * 256, kr = f >> 4, nq = f & 15;
      float4 v = *(const float4*)&mem[(size_t)(k0 + kr) * 1024 + n0 + nq * 4];
      ((float4*)Bs)[kr * 16 + ((nq ^ (kr >> 2)) & 15)] = v;
    }
    mm_inner(As, Bs, ridx, cidx, acc);
  }
  int gcol = n0 + cidx * 4;
#pragma unroll
  for (int i = 0; i < 4; ++i) {
    int row = ridx * 4 + i;
    *(float4*)&fin[(size_t)row * 4096 + 3072 + gcol] =
        make_float4(acc[i][0], acc[i][1], acc[i][2], acc[i][3]);
  }
}

// ---------------- action logits: [64,30] = ha @ Wa2^T + ba2 ----------------
__global__ __launch_bounds__(256) void k_actlog(
    const float* __restrict__ ha, const float* __restrict__ Wa2,
    const float* __restrict__ ba2, float* __restrict__ out) {
  int t = blockIdx.x, tid = threadIdx.x;
  int v = tid >> 3, p = tid & 7;
  float sum = 0.f;
  if (v < VA) {
    const float* a  = ha + (size_t)t * 1024 + p * 128;
    const float* wr = Wa2 + (size_t)v * 1024 + p * 128;
#pragma unroll 8
    for (int i = 0; i < 128; i += 4) {
      float4 av = *(const float4*)(a + i);
      float4 wv = *(const float4*)(wr + i);
      sum += av.x * wv.x + av.y * wv.y + av.z * wv.z + av.w * wv.w;
    }
  }
  sum += __shfl_xor(sum, 1);
  sum += __shfl_xor(sum, 2);
  sum += __shfl_xor(sum, 4);
  if (p == 0 && v < VA) out[(size_t)t * VA + v] = sum + ba2[v];
}

extern "C" void kernel_launch(void* const* d_in, const int* in_sizes, int n_in,
                              void* d_out, int out_size, void* d_ws, size_t ws_size,
                              hipStream_t stream) {
  const float* memory   = (const float*)d_in[0];
  const int*   actions  = (const int*)d_in[1];
  const int*   words    = (const int*)d_in[2];
  const float* term_Wih = (const float*)d_in[3];
  const float* term_Whh = (const float*)d_in[4];
  const float* term_bih = (const float*)d_in[5];
  const float* term_bhh = (const float*)d_in[6];
  const float* act_Wih  = (const float*)d_in[7];
  const float* act_Whh  = (const float*)d_in[8];
  const float* act_bih  = (const float*)d_in[9];
  const float* act_bhh  = (const float*)d_in[10];
  const float* Wq  = (const float*)d_in[11];
  const float* bq  = (const float*)d_in[12];
  const float* Wa1 = (const float*)d_in[13];
  const float* ba1 = (const float*)d_in[14];
  const float* Wa2 = (const float*)d_in[15];
  const float* ba2 = (const float*)d_in[16];
  const float* Ww1 = (const float*)d_in[17];
  const float* bw1 = (const float*)d_in[18];
  const float* Ww2 = (const float*)d_in[19];
  const float* bw2 = (const float*)d_in[20];
  const float* act_emb  = (const float*)d_in[21];
  const float* word_emb = (const float*)d_in[22];
  float* out = (float*)d_out;

  // workspace (floats); post-recur buffers overlap the Pxg region
  float* w     = (float*)d_ws;
  float* fin   = w;                       // 262144
  u64*   htag  = (u64*)(w + 262144);      // 131072 u64
  float* Pxg_t = w + 525312;              // 524288
  float* Pxg_a = w + 1049600;             // 524288
  float* qbuf  = w + 525312;              // 65536   (reuses Pxg after recur)
  float* Pa    = w + 590848;              // 262144
  float* ha    = w + 852992;              // 65536
  float* hw    = w + 918528;              // 65536

  k_head<<<dim3(65, 2, 2), 256, 0, stream>>>(
      actions, words, act_emb, word_emb, term_Wih, act_Wih,
      Pxg_t, Pxg_a, fin, htag);

  k_recur<<<256, 256, 0, stream>>>(term_Whh, act_Whh, Pxg_t, Pxg_a,
                                   term_bih, term_bhh, act_bih, act_bhh, fin, htag);

  // q = states @ Wq^T + bq   (MFMA, N=1024, K=3072)
  k_mfma_bt<<<dim3(64, 1), 256, 0, stream>>>(
      fin, 4096, Wq, nullptr, 3072, bq, nullptr, qbuf, nullptr, 1024, 3072, 0);

  // attn partials (fp32, splitk=8)
  k_attn2<<<dim3(8, 8), 256, 0, stream>>>(qbuf, memory, Pa);

  // ctx -> fin[:,3072:4096]  (fp32, splitk=1)
  k_ctx2<<<16, 256, 0, stream>>>(Pa, memory, fin);

  // ha = relu(final@Wa1^T+ba1), hw = relu(final@Ww1^T+bw1)  (MFMA dual, K=4096)
  k_mfma_bt<<<dim3(64, 2), 256, 0, stream>>>(
      fin, 4096, Wa1, Ww1, 4096, ba1, bw1, ha, hw, 1024, 4096, 1);

  // act logits
  k_actlog<<<64, 256, 0, stream>>>(ha, Wa2, ba2, out);

  // word logits (MFMA, N=30000, K=1024)
  k_mfma_bt<<<dim3(1875, 1), 256, 0, stream>>>(
      hw, 1024, Ww2, nullptr, 1024, bw2, nullptr, out + 1920, nullptr, VW, 1024, 0);
}